// Round 19
// baseline (191.298 us; speedup 1.0000x reference)
//
#include <hip/hip_runtime.h>
#include <stdint.h>

#define S_LEN 2048
#define DK 1024
#define NH 16
#define DH 64
#define LOG2E 1.4426950408889634f
#define M_FIX 10.0f

typedef __attribute__((ext_vector_type(8))) short bf16x8;
typedef __attribute__((ext_vector_type(4))) float f32x4;

__device__ __forceinline__ unsigned short f2bf(float f) {
    union { float f; uint32_t u; } v; v.f = f;
    return (unsigned short)((v.u + 0x7fffu + ((v.u >> 16) & 1u)) >> 16);
}

__device__ __forceinline__ float fast_exp2(float x) {
#if __has_builtin(__builtin_amdgcn_exp2f)
    return __builtin_amdgcn_exp2f(x);
#else
    return exp2f(x);
#endif
}

// packed f32 pair -> [lo16=bf16(a), hi16=bf16(b)] in one VALU op (RNE)
__device__ __forceinline__ uint32_t cvt_pk_bf16(float a, float b) {
    uint32_t r;
    asm("v_cvt_pk_bf16_f32 %0, %1, %2" : "=v"(r) : "v"(a), "v"(b));
    return r;
}

__device__ __forceinline__ void gload_lds16(const void* g, void* l) {
    __builtin_amdgcn_global_load_lds((const __attribute__((address_space(1))) void*)g,
                                     (__attribute__((address_space(3))) void*)l, 16, 0, 0);
}

// ---------------- f32 -> bf16 convert: all 7 tensors in one launch ----------------
__global__ __launch_bounds__(256) void cvt7_kernel(
    const float* __restrict__ a0, const float* __restrict__ a1, const float* __restrict__ a2,
    const float* __restrict__ a3, const float* __restrict__ a4, const float* __restrict__ a5,
    const float* __restrict__ a6,
    unsigned short* __restrict__ o0, unsigned short* __restrict__ o1, unsigned short* __restrict__ o2,
    unsigned short* __restrict__ o3, unsigned short* __restrict__ o4, unsigned short* __restrict__ o5,
    unsigned short* __restrict__ o6,
    int n4_big, int n4_w, int n4_f)
{
    const int y = blockIdx.y;
    const float* in = (y == 0) ? a0 : (y == 1) ? a1 : (y == 2) ? a2 :
                      (y == 3) ? a3 : (y == 4) ? a4 : (y == 5) ? a5 : a6;
    unsigned short* out = (y == 0) ? o0 : (y == 1) ? o1 : (y == 2) ? o2 :
                          (y == 3) ? o3 : (y == 4) ? o4 : (y == 5) ? o5 : o6;
    const int n4 = (y < 3) ? n4_big : ((y < 6) ? n4_w : n4_f);
    const float4* pin = (const float4*)in;
    ushort4* pout = (ushort4*)out;
    int i = blockIdx.x * blockDim.x + threadIdx.x;
    int stride = gridDim.x * blockDim.x;
    for (; i < n4; i += stride) {
        float4 v = pin[i];
        ushort4 o;
        o.x = f2bf(v.x); o.y = f2bf(v.y); o.z = f2bf(v.z); o.w = f2bf(v.w);
        pout[i] = o;
    }
}

// ---------------- QKV projection GEMM (128x256 tile, 3+3 buf, depth-2 counted-vmcnt) ----------------
// Same proven skeleton as r18 (2-deep prefetch, counted vmcnt, raw s_barrier,
// rotation LDS) with a 2x wider n-tile: 32 MFMA per barrier per wave (was 16),
// amortizing the per-step sync/drain fixed cost. LDS 72KB -> 2 blocks/CU
// (8 waves). Per stage 6 gloads/wave -> vmcnt(6) retires stage(t) with
// stage(t+1) still in flight across two compute phases.
__global__ __launch_bounds__(256, 2) void proj_gemm(
    const unsigned short* __restrict__ Xq, const unsigned short* __restrict__ Xk, const unsigned short* __restrict__ Xv,
    const unsigned short* __restrict__ Wq, const unsigned short* __restrict__ Wk, const unsigned short* __restrict__ Wv,
    const float* __restrict__ bq, const float* __restrict__ bk, const float* __restrict__ bv,
    unsigned short* __restrict__ Qh, unsigned short* __restrict__ Kh, unsigned short* __restrict__ Vt)
{
    // bijective remap: d = x + 4y + 256z (768 blocks); k = XCD slot
    const int d = blockIdx.x + (blockIdx.y << 2) + (blockIdx.z << 8);
    const int k = d & 7, s = d >> 3;
    const int nn = s & 3;                  // 4 n-tiles of 256
    const int mz = ((s >> 2) << 3) + k;    // 0..191
    const int m0 = (mz & 63) * 128;
    const int z = mz >> 6;

    const unsigned short* X = (z == 0) ? Xq : ((z == 1) ? Xk : Xv);
    const unsigned short* W = (z == 0) ? Wq : ((z == 1) ? Wk : Wv);
    const float* bias = (z == 0) ? bq : ((z == 1) ? bk : bv);

    const int n0 = nn * 256;
    const int tid = threadIdx.x;
    const int w = tid >> 6;
    const int l = tid & 63;
    const int wm = w >> 1, wn = w & 1;
    const int g = l >> 4, c = l & 15;

    __shared__ __align__(16) unsigned short As[3][128 * 32];
    __shared__ __align__(16) unsigned short Bs[3][256 * 32];

    f32x4 acc[4][8] = {};

    const int srow = l >> 2;
    const int schunk = (((l & 3) - (l >> 3)) & 3) * 8;   // rotation: slot t holds chunk (t-(row>>1))&3

    auto stage = [&](int kk, int buf) {
#pragma unroll
        for (int j = 0; j < 2; ++j) {
            int r0 = 32 * w + 16 * j;
            gload_lds16(X + (size_t)(m0 + r0 + srow) * DK + kk + schunk, &As[buf][r0 * 32]);
        }
#pragma unroll
        for (int j = 0; j < 4; ++j) {
            int r0 = 64 * w + 16 * j;
            gload_lds16(W + (size_t)(n0 + r0 + srow) * DK + kk + schunk, &Bs[buf][r0 * 32]);
        }
    };

    // prologue: 2-deep prefetch (12 gloads/wave outstanding)
    stage(0, 0);
    stage(32, 1);

    int cur = 0;
    for (int step = 0; step < 32; ++step) {
        if (step < 31) asm volatile("s_waitcnt vmcnt(6)" ::: "memory");
        else           asm volatile("s_waitcnt vmcnt(0)" ::: "memory");
        __builtin_amdgcn_s_barrier();
        __builtin_amdgcn_sched_barrier(0);

        if (step < 30) {
            int nb = cur + 2; if (nb >= 3) nb -= 3;
            stage((step + 2) << 5, nb);
        }

        bf16x8 a[4], bb[8];
        const int rchunk = 8 * ((g + (c >> 1)) & 3);   // conflict-free rotation read
#pragma unroll
        for (int mi = 0; mi < 4; ++mi)
            a[mi] = *(const bf16x8*)&As[cur][(64 * wm + 16 * mi + c) * 32 + rchunk];
#pragma unroll
        for (int nj = 0; nj < 8; ++nj)
            bb[nj] = *(const bf16x8*)&Bs[cur][(128 * wn + 16 * nj + c) * 32 + rchunk];
        __builtin_amdgcn_s_setprio(1);
#pragma unroll
        for (int mi = 0; mi < 4; ++mi)
#pragma unroll
            for (int nj = 0; nj < 8; ++nj)
                acc[mi][nj] = __builtin_amdgcn_mfma_f32_16x16x32_bf16(a[mi], bb[nj], acc[mi][nj], 0, 0, 0);
        __builtin_amdgcn_s_setprio(0);

        ++cur; if (cur == 3) cur = 0;
    }

    // Q pre-scaled by LOG2E/8 (attn exp2's the raw QK^T sum)
    const float scale = (z == 0) ? (0.125f * LOG2E) : 1.0f;
#pragma unroll
    for (int mi = 0; mi < 4; ++mi) {
#pragma unroll
        for (int nj = 0; nj < 8; ++nj) {
            int col = n0 + 128 * wn + 16 * nj + c;
            float bval = bias[col];
            int h = col >> 6, dh = col & 63;
            int row0 = m0 + 64 * wm + 16 * mi + 4 * g;
            int b = row0 >> 11, ss = row0 & 2047;
            if (z != 2) {
                unsigned short* Out = (z == 0) ? Qh : Kh;
#pragma unroll
                for (int r = 0; r < 4; ++r) {
                    float v = (acc[mi][nj][r] + bval) * scale;
                    Out[((size_t)(b * NH + h) * S_LEN + (ss + r)) * DH + dh] = f2bf(v);
                }
            } else {
                ushort4 o;
                o.x = f2bf(acc[mi][nj][0] + bval);
                o.y = f2bf(acc[mi][nj][1] + bval);
                o.z = f2bf(acc[mi][nj][2] + bval);
                o.w = f2bf(acc[mi][nj][3] + bval);
                // pair-interleaved key order within each 32-block
                int q = (ss >> 2) & 7;
                int newpos = (ss & ~31) + 8 * (q & 3) + 4 * (q >> 2);
                *(ushort4*)&Vt[((size_t)(b * NH + h) * DH + dh) * S_LEN + newpos] = o;
            }
        }
    }
}

// ---------------- Flash attention (KVBLK=64: one barrier per 64 keys) ----------------
// Unchanged from round-18 green (~70 us, 0 bank conflicts).
__global__ __launch_bounds__(256, 4) void attn_kernel(
    const unsigned short* __restrict__ Qh, const unsigned short* __restrict__ Kh,
    const unsigned short* __restrict__ Vt, const int* __restrict__ maskI,
    unsigned short* __restrict__ O)
{
    // XCD swizzle: 1024 wgs, 8 XCDs -> 128 contiguous wgs per XCD (8 bh each)
    const int id = blockIdx.x + (blockIdx.y << 4);
    const int swzid = (id & 7) * 128 + (id >> 3);
    const int q0 = (swzid & 15) * 128;
    const int bh = swzid >> 4;
    const int b = bh >> 4, h = bh & 15;
    const int tid = threadIdx.x, w = tid >> 6, l = tid & 63;
    const int g = l >> 4, c = l & 15;

    __shared__ __align__(16) unsigned short Ks[2][4096];   // [u][32key x 64dh] x2 sub-tiles
    __shared__ __align__(16) unsigned short Vs[2][4096];   // [u][64dh x 32key] pair-rotated
    __shared__ __align__(16) float mskA[S_LEN];

    bf16x8 qf[2][2];
    const size_t qbase = (size_t)bh * S_LEN + q0 + 32 * w;
#pragma unroll
    for (int mi = 0; mi < 2; ++mi)
#pragma unroll
        for (int k32 = 0; k32 < 2; ++k32)
            qf[mi][k32] = *(const bf16x8*)&Qh[(qbase + 16 * mi + c) * DH + k32 * 32 + 8 * g];

    f32x4 ao[2][4] = {};
    f32x4 ls[2] = {};
    bf16x8 ones;
#pragma unroll
    for (int j = 0; j < 8; ++j) ones[j] = (short)0x3F80;  // bf16 1.0

    // staging source swizzles
    const int kswz = ((l & 7) ^ (l >> 3)) * 8;               // K: 8-chunk XOR (conflict-free)
    const int vrow = l >> 2;                                 // V: stage row within wave's 16
    const int vsrc = (((l & 3) - (l >> 3)) & 3) * 8;         // quad-pair rotation source

    auto stageKV = [&](int kv, int buf) {
#pragma unroll
        for (int u = 0; u < 2; ++u) {
            int kvs = kv + 32 * u;
            gload_lds16(Kh + ((size_t)bh * S_LEN + kvs + 8 * w + (l >> 3)) * DH + kswz,
                        &Ks[buf][u * 2048 + w * 512]);
            gload_lds16(Vt + ((size_t)bh * DH + 16 * w + vrow) * S_LEN + kvs + vsrc,
                        &Vs[buf][u * 2048 + w * 512]);
        }
    };

    // prologue: stage tile 0 + mask preload
    stageKV(0, 0);
    {
        const int4* mp = (const int4*)(maskI + b * S_LEN);
#pragma unroll
        for (int i = 0; i < 2; ++i) {
            int idx = tid + 256 * i;
            int4 m = mp[idx];
            float4 f;
            f.x = m.x ? (-M_FIX * LOG2E) : -3e38f;
            f.y = m.y ? (-M_FIX * LOG2E) : -3e38f;
            f.z = m.z ? (-M_FIX * LOG2E) : -3e38f;
            f.w = m.w ? (-M_FIX * LOG2E) : -3e38f;
            *(float4*)&mskA[idx * 4] = f;
        }
    }

    for (int t = 0; t < 32; ++t) {
        const int cur = t & 1;
        const int kv0 = t << 6;
        __syncthreads();   // stage(t) drained (vmcnt0+lgkm0); prev tile's LDS reads done

        if (t < 31) stageKV(kv0 + 64, cur ^ 1);

#pragma unroll
        for (int u = 0; u < 2; ++u) {
            const int base = u * 2048;
            const int kv0s = kv0 + 32 * u;

            // mask bias (also the QK C-operand), hoisted above the MFMAs
            float4 mk0 = *(const float4*)&mskA[kv0s + 4 * g];
            float4 mk1 = *(const float4*)&mskA[kv0s + 16 + 4 * g];
            f32x4 sf[2][2];
            sf[0][0] = f32x4{mk0.x, mk0.y, mk0.z, mk0.w};
            sf[1][0] = sf[0][0];
            sf[0][1] = f32x4{mk1.x, mk1.y, mk1.z, mk1.w};
            sf[1][1] = sf[0][1];

            // Swapped QK^T: sf[mi][nj] = D[key=16nj+4g+r][q=16mi+c] + mask bias
            __builtin_amdgcn_s_setprio(1);
#pragma unroll
            for (int nj = 0; nj < 2; ++nj) {
                int krow = 16 * nj + c;
#pragma unroll
                for (int k32 = 0; k32 < 2; ++k32) {
                    int chunk = (k32 * 4 + g) ^ (krow & 7);
                    bf16x8 kf = *(const bf16x8*)&Ks[cur][base + krow * 64 + chunk * 8];
#pragma unroll
                    for (int mi = 0; mi < 2; ++mi)
                        sf[mi][nj] = __builtin_amdgcn_mfma_f32_16x16x32_bf16(kf, qf[mi][k32], sf[mi][nj], 0, 0, 0);
                }
            }
            __builtin_amdgcn_s_setprio(0);

            // softmax: p = exp2(sf) directly (scale+mask pre-folded)
            bf16x8 pf[2];
#pragma unroll
            for (int mi = 0; mi < 2; ++mi) {
                float e00 = fast_exp2(sf[mi][0][0]);
                float e01 = fast_exp2(sf[mi][0][1]);
                float e02 = fast_exp2(sf[mi][0][2]);
                float e03 = fast_exp2(sf[mi][0][3]);
                float e10 = fast_exp2(sf[mi][1][0]);
                float e11 = fast_exp2(sf[mi][1][1]);
                float e12 = fast_exp2(sf[mi][1][2]);
                float e13 = fast_exp2(sf[mi][1][3]);
                union { uint32_t u2[4]; bf16x8 v; } pu;
                pu.u2[0] = cvt_pk_bf16(e00, e01);
                pu.u2[1] = cvt_pk_bf16(e02, e03);
                pu.u2[2] = cvt_pk_bf16(e10, e11);
                pu.u2[3] = cvt_pk_bf16(e12, e13);
                pf[mi] = pu.v;
            }

            // PV: ao += P.V^T (k-axis = pi(g,j)); ls += P.1
            __builtin_amdgcn_s_setprio(1);
#pragma unroll
            for (int nc = 0; nc < 4; ++nc) {
                int row = 16 * nc + c;
                int s16 = (g + (c >> 1)) & 3;
                bf16x8 vf = *(const bf16x8*)&Vs[cur][base + row * 32 + 8 * s16];
#pragma unroll
                for (int mi = 0; mi < 2; ++mi)
                    ao[mi][nc] = __builtin_amdgcn_mfma_f32_16x16x32_bf16(pf[mi], vf, ao[mi][nc], 0, 0, 0);
            }
#pragma unroll
            for (int mi = 0; mi < 2; ++mi)
                ls[mi] = __builtin_amdgcn_mfma_f32_16x16x32_bf16(pf[mi], ones, ls[mi], 0, 0, 0);
            __builtin_amdgcn_s_setprio(0);
        }
    }

#pragma unroll
    for (int mi = 0; mi < 2; ++mi)
#pragma unroll
        for (int r = 0; r < 4; ++r) {
            int s = q0 + 32 * w + 16 * mi + 4 * g + r;
            float inv = 1.0f / ls[mi][r];
#pragma unroll
            for (int nc = 0; nc < 4; ++nc) {
                int dh = 16 * nc + c;
                O[(size_t)(b * S_LEN + s) * 1024 + h * DH + dh] = f2bf(ao[mi][nc][r] * inv);
            }
        }
}

// ---------------- fc GEMM + grouped softmax (3-buf counted-vmcnt pipeline) ----------------
__global__ __launch_bounds__(256) void fc_kernel(
    const unsigned short* __restrict__ O, const unsigned short* __restrict__ Wf,
    const float* __restrict__ bfc, float* __restrict__ out)
{
    const int m0 = blockIdx.x * 64;
    const int tid = threadIdx.x, w = tid >> 6, l = tid & 63;
    const int g = l >> 4, c = l & 15;

    __shared__ __align__(16) unsigned short As[3][64 * 32];
    __shared__ __align__(16) unsigned short Bs[3][128 * 32];

    f32x4 acc[8] = {};

    const int srow = l >> 2;
    const int schunk = (((l & 3) - (l >> 3)) & 3) * 8;

    auto stage = [&](int kk, int buf) {
        gload_lds16(O + (size_t)(m0 + 16 * w + srow) * DK + kk + schunk, &As[buf][16 * w * 32]);
#pragma unroll
        for (int j = 0; j < 2; ++j) {
            int r0 = 32 * w + 16 * j;
            gload_lds16(Wf + (size_t)(r0 + srow) * DK + kk + schunk, &Bs[buf][r0 * 32]);
        }
    };

    stage(0, 0);
    stage(32, 1);

    int cur = 0;
    for (int step = 0; step < 32; ++step) {
        if (step < 31) asm volatile("s_waitcnt vmcnt(3)" ::: "memory");
        else           asm volatile("s_waitcnt vmcnt(0)" ::: "memory");
        __builtin_amdgcn_s_barrier();
        __builtin_amdgcn_sched_barrier(0);

        if (step < 30) {
            int nb = cur + 2; if (nb >= 3) nb -= 3;
            stage((step + 2) << 5, nb);
        }

        const int rchunk = 8 * ((g + (c >> 1)) & 3);
        bf16x8 a = *(const bf16x8*)&As[cur][(16 * w + c) * 32 + rchunk];
        bf16x8 bb[8];
#pragma unroll
        for (int nj = 0; nj < 8; ++nj)
            bb[nj] = *(const bf16x8*)&Bs[cur][(16 * nj + c) * 32 + rchunk];
        __builtin_amdgcn_s_setprio(1);
#pragma unroll
        for (int nj = 0; nj < 8; ++nj)
            acc[nj] = __builtin_amdgcn_mfma_f32_16x16x32_bf16(a, bb[nj], acc[nj], 0, 0, 0);
        __builtin_amdgcn_s_setprio(0);

        ++cur; if (cur == 3) cur = 0;
    }

#pragma unroll
    for (int r = 0; r < 4; ++r) {
        int row = m0 + 16 * w + (l >> 4) * 4 + r;
#pragma unroll
        for (int par = 0; par < 2; ++par) {
            float v[4];
#pragma unroll
            for (int e = 0; e < 4; ++e) {
                int col = 16 * (2 * e + par) + (l & 15);
                v[e] = acc[2 * e + par][r] + bfc[col];
            }
            float mx = fmaxf(fmaxf(v[0], v[1]), fmaxf(v[2], v[3]));
            float ex[4], ssum = 0.f;
#pragma unroll
            for (int e = 0; e < 4; ++e) { ex[e] = fast_exp2((v[e] - mx) * LOG2E); ssum += ex[e]; }
            float inv = 1.0f / ssum;
#pragma unroll
            for (int e = 0; e < 4; ++e) {
                int col = 16 * (2 * e + par) + (l & 15);
                out[(size_t)row * 128 + col] = ex[e] * inv;
            }
        }
    }
}

extern "C" void kernel_launch(void* const* d_in, const int* in_sizes, int n_in,
                              void* d_out, int out_size, void* d_ws, size_t ws_size,
                              hipStream_t stream) {
    (void)in_sizes; (void)n_in; (void)out_size; (void)ws_size;
    const float* q    = (const float*)d_in[0];
    const float* k    = (const float*)d_in[1];
    const float* v    = (const float*)d_in[2];
    const int*   mask = (const int*)d_in[3];
    const float* wq_w = (const float*)d_in[4];
    const float* wq_b = (const float*)d_in[5];
    const float* wk_w = (const float*)d_in[6];
    const float* wk_b = (const float*)d_in[7];
    const float* wv_w = (const float*)d_in[8];
    const float* wv_b = (const float*)d_in[9];
    const float* fc_w = (const float*)d_in[10];
    const float* fc_b = (const float*)d_in[11];

    const size_t NX = (size_t)8192 * 1024;
    const size_t NW = (size_t)1024 * 1024;
    const size_t NF = (size_t)128 * 1024;

    unsigned short* Xq = (unsigned short*)d_ws;
    unsigned short* Xk = Xq + NX;
    unsigned short* Xv = Xk + NX;
    unsigned short* Wq = Xv + NX;
    unsigned short* Wk = Wq + NW;
    unsigned short* Wv = Wk + NW;
    unsigned short* Wf = Wv + NW;
    unsigned short* Qh = Wf + NF;
    unsigned short* Kh = Qh + NX;
    unsigned short* Vt = Kh + NX;
    unsigned short* O  = Xq;  // Xq dead after proj; reuse for attention output

    cvt7_kernel<<<dim3(2048, 7), 256, 0, stream>>>(q, k, v, wq_w, wk_w, wv_w, fc_w,
                                                   Xq, Xk, Xv, Wq, Wk, Wv, Wf,
                                                   (int)(NX / 4), (int)(NW / 4), (int)(NF / 4));

    proj_gemm<<<dim3(4, 64, 3), 256, 0, stream>>>(Xq, Xk, Xv, Wq, Wk, Wv,
                                                  wq_b, wk_b, wv_b, Qh, Kh, Vt);
    attn_kernel<<<dim3(16, 64), 256, 0, stream>>>(Qh, Kh, Vt, mask, O);
    fc_kernel<<<128, 256, 0, stream>>>(O, Wf, fc_b, (float*)d_out);
}

// Round 20
// 184.406 us; speedup vs baseline: 1.0374x; 1.0374x over previous
//
#include <hip/hip_runtime.h>
#include <stdint.h>

#define S_LEN 2048
#define DK 1024
#define NH 16
#define DH 64
#define LOG2E 1.4426950408889634f
#define M_FIX 10.0f

typedef __attribute__((ext_vector_type(8))) short bf16x8;
typedef __attribute__((ext_vector_type(4))) float f32x4;

__device__ __forceinline__ unsigned short f2bf(float f) {
    union { float f; uint32_t u; } v; v.f = f;
    return (unsigned short)((v.u + 0x7fffu + ((v.u >> 16) & 1u)) >> 16);
}

__device__ __forceinline__ float fast_exp2(float x) {
#if __has_builtin(__builtin_amdgcn_exp2f)
    return __builtin_amdgcn_exp2f(x);
#else
    return exp2f(x);
#endif
}

// packed f32 pair -> [lo16=bf16(a), hi16=bf16(b)] in one VALU op (RNE)
__device__ __forceinline__ uint32_t cvt_pk_bf16(float a, float b) {
    uint32_t r;
    asm("v_cvt_pk_bf16_f32 %0, %1, %2" : "=v"(r) : "v"(a), "v"(b));
    return r;
}

__device__ __forceinline__ void gload_lds16(const void* g, void* l) {
    __builtin_amdgcn_global_load_lds((const __attribute__((address_space(1))) void*)g,
                                     (__attribute__((address_space(3))) void*)l, 16, 0, 0);
}

// ---------------- f32 -> bf16 convert: all 7 tensors in one launch ----------------
__global__ __launch_bounds__(256) void cvt7_kernel(
    const float* __restrict__ a0, const float* __restrict__ a1, const float* __restrict__ a2,
    const float* __restrict__ a3, const float* __restrict__ a4, const float* __restrict__ a5,
    const float* __restrict__ a6,
    unsigned short* __restrict__ o0, unsigned short* __restrict__ o1, unsigned short* __restrict__ o2,
    unsigned short* __restrict__ o3, unsigned short* __restrict__ o4, unsigned short* __restrict__ o5,
    unsigned short* __restrict__ o6,
    int n4_big, int n4_w, int n4_f)
{
    const int y = blockIdx.y;
    const float* in = (y == 0) ? a0 : (y == 1) ? a1 : (y == 2) ? a2 :
                      (y == 3) ? a3 : (y == 4) ? a4 : (y == 5) ? a5 : a6;
    unsigned short* out = (y == 0) ? o0 : (y == 1) ? o1 : (y == 2) ? o2 :
                          (y == 3) ? o3 : (y == 4) ? o4 : (y == 5) ? o5 : o6;
    const int n4 = (y < 3) ? n4_big : ((y < 6) ? n4_w : n4_f);
    const float4* pin = (const float4*)in;
    ushort4* pout = (ushort4*)out;
    int i = blockIdx.x * blockDim.x + threadIdx.x;
    int stride = gridDim.x * blockDim.x;
    for (; i < n4; i += stride) {
        float4 v = pin[i];
        ushort4 o;
        o.x = f2bf(v.x); o.y = f2bf(v.y); o.z = f2bf(v.z); o.w = f2bf(v.w);
        pout[i] = o;
    }
}

// ---------------- QKV projection GEMM (128x128, 512 threads / 8 waves) ----------------
// Same r18-green skeleton (BK=32, 3+3 buffers, depth-2 counted vmcnt, raw
// s_barrier, rotation LDS) with 8 waves (2m x 4n grid, 64x32 wave-tile):
// waves/SIMD 3 -> 6 to hide the per-step barrier/drain fixed cost. Per stage
// 2 gloads/thread -> vmcnt(2) retires stage(t), stage(t+1) stays in flight.
__global__ __launch_bounds__(512) void proj_gemm(
    const unsigned short* __restrict__ Xq, const unsigned short* __restrict__ Xk, const unsigned short* __restrict__ Xv,
    const unsigned short* __restrict__ Wq, const unsigned short* __restrict__ Wk, const unsigned short* __restrict__ Wv,
    const float* __restrict__ bq, const float* __restrict__ bk, const float* __restrict__ bv,
    unsigned short* __restrict__ Qh, unsigned short* __restrict__ Kh, unsigned short* __restrict__ Vt)
{
    // bijective remap: d = x + 8y + 512z; k = XCD slot, s = per-XCD sequence
    const int d = blockIdx.x + (blockIdx.y << 3) + (blockIdx.z << 9);
    const int k = d & 7, s = d >> 3;
    const int nn = s & 7;
    const int mz = ((s >> 3) << 3) + k;      // 0..191
    const int m0 = (mz & 63) * 128;
    const int z = mz >> 6;

    const unsigned short* X = (z == 0) ? Xq : ((z == 1) ? Xk : Xv);
    const unsigned short* W = (z == 0) ? Wq : ((z == 1) ? Wk : Wv);
    const float* bias = (z == 0) ? bq : ((z == 1) ? bk : bv);

    const int n0 = nn * 128;
    const int tid = threadIdx.x;
    const int w = tid >> 6;                  // 0..7
    const int l = tid & 63;
    const int wm = w >> 2, wn = w & 3;       // 2m x 4n wave grid
    const int g = l >> 4, c = l & 15;

    __shared__ __align__(16) unsigned short As[3][128 * 32];
    __shared__ __align__(16) unsigned short Bs[3][128 * 32];

    f32x4 acc[4][2] = {};

    const int srow = l >> 2;                                 // 0..15 row within wave's 16
    const int schunk = (((l & 3) - (l >> 3)) & 3) * 8;       // rotation source chunk

    auto stage = [&](int kk, int buf) {
        int r0 = 16 * w;                                     // wave w: rows 16w..16w+15
        gload_lds16(X + (size_t)(m0 + r0 + srow) * DK + kk + schunk, &As[buf][r0 * 32]);
        gload_lds16(W + (size_t)(n0 + r0 + srow) * DK + kk + schunk, &Bs[buf][r0 * 32]);
    };

    // prologue: 2-deep prefetch (4 gloads/thread outstanding)
    stage(0, 0);
    stage(32, 1);

    int cur = 0;
    for (int step = 0; step < 32; ++step) {
        if (step < 31) asm volatile("s_waitcnt vmcnt(2)" ::: "memory");
        else           asm volatile("s_waitcnt vmcnt(0)" ::: "memory");
        __builtin_amdgcn_s_barrier();
        __builtin_amdgcn_sched_barrier(0);

        if (step < 30) {
            int nb = cur + 2; if (nb >= 3) nb -= 3;
            stage((step + 2) << 5, nb);
        }

        bf16x8 a[4], bb[2];
        const int rchunk = 8 * ((g + (c >> 1)) & 3);   // conflict-free rotation read
#pragma unroll
        for (int mi = 0; mi < 4; ++mi)
            a[mi] = *(const bf16x8*)&As[cur][(64 * wm + 16 * mi + c) * 32 + rchunk];
#pragma unroll
        for (int nj = 0; nj < 2; ++nj)
            bb[nj] = *(const bf16x8*)&Bs[cur][(32 * wn + 16 * nj + c) * 32 + rchunk];
        __builtin_amdgcn_s_setprio(1);
#pragma unroll
        for (int mi = 0; mi < 4; ++mi)
#pragma unroll
            for (int nj = 0; nj < 2; ++nj)
                acc[mi][nj] = __builtin_amdgcn_mfma_f32_16x16x32_bf16(a[mi], bb[nj], acc[mi][nj], 0, 0, 0);
        __builtin_amdgcn_s_setprio(0);

        ++cur; if (cur == 3) cur = 0;
    }

    // Q pre-scaled by LOG2E/8 (attn exp2's the raw QK^T sum)
    const float scale = (z == 0) ? (0.125f * LOG2E) : 1.0f;
#pragma unroll
    for (int mi = 0; mi < 4; ++mi) {
#pragma unroll
        for (int nj = 0; nj < 2; ++nj) {
            int col = n0 + 32 * wn + 16 * nj + c;
            float bval = bias[col];
            int h = col >> 6, dh = col & 63;
            int row0 = m0 + 64 * wm + 16 * mi + 4 * g;
            int b = row0 >> 11, ss = row0 & 2047;
            if (z != 2) {
                unsigned short* Out = (z == 0) ? Qh : Kh;
#pragma unroll
                for (int r = 0; r < 4; ++r) {
                    float v = (acc[mi][nj][r] + bval) * scale;
                    Out[((size_t)(b * NH + h) * S_LEN + (ss + r)) * DH + dh] = f2bf(v);
                }
            } else {
                ushort4 o;
                o.x = f2bf(acc[mi][nj][0] + bval);
                o.y = f2bf(acc[mi][nj][1] + bval);
                o.z = f2bf(acc[mi][nj][2] + bval);
                o.w = f2bf(acc[mi][nj][3] + bval);
                // pair-interleaved key order within each 32-block
                int q = (ss >> 2) & 7;
                int newpos = (ss & ~31) + 8 * (q & 3) + 4 * (q >> 2);
                *(ushort4*)&Vt[((size_t)(b * NH + h) * DH + dh) * S_LEN + newpos] = o;
            }
        }
    }
}

// ---------------- Flash attention (KVBLK=64: one barrier per 64 keys) ----------------
// Unchanged from round-18 green (~70 us, 0 bank conflicts).
__global__ __launch_bounds__(256, 4) void attn_kernel(
    const unsigned short* __restrict__ Qh, const unsigned short* __restrict__ Kh,
    const unsigned short* __restrict__ Vt, const int* __restrict__ maskI,
    unsigned short* __restrict__ O)
{
    // XCD swizzle: 1024 wgs, 8 XCDs -> 128 contiguous wgs per XCD (8 bh each)
    const int id = blockIdx.x + (blockIdx.y << 4);
    const int swzid = (id & 7) * 128 + (id >> 3);
    const int q0 = (swzid & 15) * 128;
    const int bh = swzid >> 4;
    const int b = bh >> 4, h = bh & 15;
    const int tid = threadIdx.x, w = tid >> 6, l = tid & 63;
    const int g = l >> 4, c = l & 15;

    __shared__ __align__(16) unsigned short Ks[2][4096];   // [u][32key x 64dh] x2 sub-tiles
    __shared__ __align__(16) unsigned short Vs[2][4096];   // [u][64dh x 32key] pair-rotated
    __shared__ __align__(16) float mskA[S_LEN];

    bf16x8 qf[2][2];
    const size_t qbase = (size_t)bh * S_LEN + q0 + 32 * w;
#pragma unroll
    for (int mi = 0; mi < 2; ++mi)
#pragma unroll
        for (int k32 = 0; k32 < 2; ++k32)
            qf[mi][k32] = *(const bf16x8*)&Qh[(qbase + 16 * mi + c) * DH + k32 * 32 + 8 * g];

    f32x4 ao[2][4] = {};
    f32x4 ls[2] = {};
    bf16x8 ones;
#pragma unroll
    for (int j = 0; j < 8; ++j) ones[j] = (short)0x3F80;  // bf16 1.0

    // staging source swizzles
    const int kswz = ((l & 7) ^ (l >> 3)) * 8;               // K: 8-chunk XOR (conflict-free)
    const int vrow = l >> 2;                                 // V: stage row within wave's 16
    const int vsrc = (((l & 3) - (l >> 3)) & 3) * 8;         // quad-pair rotation source

    auto stageKV = [&](int kv, int buf) {
#pragma unroll
        for (int u = 0; u < 2; ++u) {
            int kvs = kv + 32 * u;
            gload_lds16(Kh + ((size_t)bh * S_LEN + kvs + 8 * w + (l >> 3)) * DH + kswz,
                        &Ks[buf][u * 2048 + w * 512]);
            gload_lds16(Vt + ((size_t)bh * DH + 16 * w + vrow) * S_LEN + kvs + vsrc,
                        &Vs[buf][u * 2048 + w * 512]);
        }
    };

    // prologue: stage tile 0 + mask preload
    stageKV(0, 0);
    {
        const int4* mp = (const int4*)(maskI + b * S_LEN);
#pragma unroll
        for (int i = 0; i < 2; ++i) {
            int idx = tid + 256 * i;
            int4 m = mp[idx];
            float4 f;
            f.x = m.x ? (-M_FIX * LOG2E) : -3e38f;
            f.y = m.y ? (-M_FIX * LOG2E) : -3e38f;
            f.z = m.z ? (-M_FIX * LOG2E) : -3e38f;
            f.w = m.w ? (-M_FIX * LOG2E) : -3e38f;
            *(float4*)&mskA[idx * 4] = f;
        }
    }

    for (int t = 0; t < 32; ++t) {
        const int cur = t & 1;
        const int kv0 = t << 6;
        __syncthreads();   // stage(t) drained (vmcnt0+lgkm0); prev tile's LDS reads done

        if (t < 31) stageKV(kv0 + 64, cur ^ 1);

#pragma unroll
        for (int u = 0; u < 2; ++u) {
            const int base = u * 2048;
            const int kv0s = kv0 + 32 * u;

            // mask bias (also the QK C-operand), hoisted above the MFMAs
            float4 mk0 = *(const float4*)&mskA[kv0s + 4 * g];
            float4 mk1 = *(const float4*)&mskA[kv0s + 16 + 4 * g];
            f32x4 sf[2][2];
            sf[0][0] = f32x4{mk0.x, mk0.y, mk0.z, mk0.w};
            sf[1][0] = sf[0][0];
            sf[0][1] = f32x4{mk1.x, mk1.y, mk1.z, mk1.w};
            sf[1][1] = sf[0][1];

            // Swapped QK^T: sf[mi][nj] = D[key=16nj+4g+r][q=16mi+c] + mask bias
            __builtin_amdgcn_s_setprio(1);
#pragma unroll
            for (int nj = 0; nj < 2; ++nj) {
                int krow = 16 * nj + c;
#pragma unroll
                for (int k32 = 0; k32 < 2; ++k32) {
                    int chunk = (k32 * 4 + g) ^ (krow & 7);
                    bf16x8 kf = *(const bf16x8*)&Ks[cur][base + krow * 64 + chunk * 8];
#pragma unroll
                    for (int mi = 0; mi < 2; ++mi)
                        sf[mi][nj] = __builtin_amdgcn_mfma_f32_16x16x32_bf16(kf, qf[mi][k32], sf[mi][nj], 0, 0, 0);
                }
            }
            __builtin_amdgcn_s_setprio(0);

            // softmax: p = exp2(sf) directly (scale+mask pre-folded)
            bf16x8 pf[2];
#pragma unroll
            for (int mi = 0; mi < 2; ++mi) {
                float e00 = fast_exp2(sf[mi][0][0]);
                float e01 = fast_exp2(sf[mi][0][1]);
                float e02 = fast_exp2(sf[mi][0][2]);
                float e03 = fast_exp2(sf[mi][0][3]);
                float e10 = fast_exp2(sf[mi][1][0]);
                float e11 = fast_exp2(sf[mi][1][1]);
                float e12 = fast_exp2(sf[mi][1][2]);
                float e13 = fast_exp2(sf[mi][1][3]);
                union { uint32_t u2[4]; bf16x8 v; } pu;
                pu.u2[0] = cvt_pk_bf16(e00, e01);
                pu.u2[1] = cvt_pk_bf16(e02, e03);
                pu.u2[2] = cvt_pk_bf16(e10, e11);
                pu.u2[3] = cvt_pk_bf16(e12, e13);
                pf[mi] = pu.v;
            }

            // PV: ao += P.V^T (k-axis = pi(g,j)); ls += P.1
            __builtin_amdgcn_s_setprio(1);
#pragma unroll
            for (int nc = 0; nc < 4; ++nc) {
                int row = 16 * nc + c;
                int s16 = (g + (c >> 1)) & 3;
                bf16x8 vf = *(const bf16x8*)&Vs[cur][base + row * 32 + 8 * s16];
#pragma unroll
                for (int mi = 0; mi < 2; ++mi)
                    ao[mi][nc] = __builtin_amdgcn_mfma_f32_16x16x32_bf16(pf[mi], vf, ao[mi][nc], 0, 0, 0);
            }
#pragma unroll
            for (int mi = 0; mi < 2; ++mi)
                ls[mi] = __builtin_amdgcn_mfma_f32_16x16x32_bf16(pf[mi], ones, ls[mi], 0, 0, 0);
            __builtin_amdgcn_s_setprio(0);
        }
    }

#pragma unroll
    for (int mi = 0; mi < 2; ++mi)
#pragma unroll
        for (int r = 0; r < 4; ++r) {
            int s = q0 + 32 * w + 16 * mi + 4 * g + r;
            float inv = 1.0f / ls[mi][r];
#pragma unroll
            for (int nc = 0; nc < 4; ++nc) {
                int dh = 16 * nc + c;
                O[(size_t)(b * S_LEN + s) * 1024 + h * DH + dh] = f2bf(ao[mi][nc][r] * inv);
            }
        }
}

// ---------------- fc GEMM + grouped softmax (3-buf counted-vmcnt pipeline) ----------------
__global__ __launch_bounds__(256) void fc_kernel(
    const unsigned short* __restrict__ O, const unsigned short* __restrict__ Wf,
    const float* __restrict__ bfc, float* __restrict__ out)
{
    const int m0 = blockIdx.x * 64;
    const int tid = threadIdx.x, w = tid >> 6, l = tid & 63;
    const int g = l >> 4, c = l & 15;

    __shared__ __align__(16) unsigned short As[3][64 * 32];
    __shared__ __align__(16) unsigned short Bs[3][128 * 32];

    f32x4 acc[8] = {};

    const int srow = l >> 2;
    const int schunk = (((l & 3) - (l >> 3)) & 3) * 8;

    auto stage = [&](int kk, int buf) {
        gload_lds16(O + (size_t)(m0 + 16 * w + srow) * DK + kk + schunk, &As[buf][16 * w * 32]);
#pragma unroll
        for (int j = 0; j < 2; ++j) {
            int r0 = 32 * w + 16 * j;
            gload_lds16(Wf + (size_t)(r0 + srow) * DK + kk + schunk, &Bs[buf][r0 * 32]);
        }
    };

    stage(0, 0);
    stage(32, 1);

    int cur = 0;
    for (int step = 0; step < 32; ++step) {
        if (step < 31) asm volatile("s_waitcnt vmcnt(3)" ::: "memory");
        else           asm volatile("s_waitcnt vmcnt(0)" ::: "memory");
        __builtin_amdgcn_s_barrier();
        __builtin_amdgcn_sched_barrier(0);

        if (step < 30) {
            int nb = cur + 2; if (nb >= 3) nb -= 3;
            stage((step + 2) << 5, nb);
        }

        const int rchunk = 8 * ((g + (c >> 1)) & 3);
        bf16x8 a = *(const bf16x8*)&As[cur][(16 * w + c) * 32 + rchunk];
        bf16x8 bb[8];
#pragma unroll
        for (int nj = 0; nj < 8; ++nj)
            bb[nj] = *(const bf16x8*)&Bs[cur][(16 * nj + c) * 32 + rchunk];
        __builtin_amdgcn_s_setprio(1);
#pragma unroll
        for (int nj = 0; nj < 8; ++nj)
            acc[nj] = __builtin_amdgcn_mfma_f32_16x16x32_bf16(a, bb[nj], acc[nj], 0, 0, 0);
        __builtin_amdgcn_s_setprio(0);

        ++cur; if (cur == 3) cur = 0;
    }

#pragma unroll
    for (int r = 0; r < 4; ++r) {
        int row = m0 + 16 * w + (l >> 4) * 4 + r;
#pragma unroll
        for (int par = 0; par < 2; ++par) {
            float v[4];
#pragma unroll
            for (int e = 0; e < 4; ++e) {
                int col = 16 * (2 * e + par) + (l & 15);
                v[e] = acc[2 * e + par][r] + bfc[col];
            }
            float mx = fmaxf(fmaxf(v[0], v[1]), fmaxf(v[2], v[3]));
            float ex[4], ssum = 0.f;
#pragma unroll
            for (int e = 0; e < 4; ++e) { ex[e] = fast_exp2((v[e] - mx) * LOG2E); ssum += ex[e]; }
            float inv = 1.0f / ssum;
#pragma unroll
            for (int e = 0; e < 4; ++e) {
                int col = 16 * (2 * e + par) + (l & 15);
                out[(size_t)row * 128 + col] = ex[e] * inv;
            }
        }
    }
}

extern "C" void kernel_launch(void* const* d_in, const int* in_sizes, int n_in,
                              void* d_out, int out_size, void* d_ws, size_t ws_size,
                              hipStream_t stream) {
    (void)in_sizes; (void)n_in; (void)out_size; (void)ws_size;
    const float* q    = (const float*)d_in[0];
    const float* k    = (const float*)d_in[1];
    const float* v    = (const float*)d_in[2];
    const int*   mask = (const int*)d_in[3];
    const float* wq_w = (const float*)d_in[4];
    const float* wq_b = (const float*)d_in[5];
    const float* wk_w = (const float*)d_in[6];
    const float* wk_b = (const float*)d_in[7];
    const float* wv_w = (const float*)d_in[8];
    const float* wv_b = (const float*)d_in[9];
    const float* fc_w = (const float*)d_in[10];
    const float* fc_b = (const float*)d_in[11];

    const size_t NX = (size_t)8192 * 1024;
    const size_t NW = (size_t)1024 * 1024;
    const size_t NF = (size_t)128 * 1024;

    unsigned short* Xq = (unsigned short*)d_ws;
    unsigned short* Xk = Xq + NX;
    unsigned short* Xv = Xk + NX;
    unsigned short* Wq = Xv + NX;
    unsigned short* Wk = Wq + NW;
    unsigned short* Wv = Wk + NW;
    unsigned short* Wf = Wv + NW;
    unsigned short* Qh = Wf + NF;
    unsigned short* Kh = Qh + NX;
    unsigned short* Vt = Kh + NX;
    unsigned short* O  = Xq;  // Xq dead after proj; reuse for attention output

    cvt7_kernel<<<dim3(2048, 7), 256, 0, stream>>>(q, k, v, wq_w, wk_w, wv_w, fc_w,
                                                   Xq, Xk, Xv, Wq, Wk, Wv, Wf,
                                                   (int)(NX / 4), (int)(NW / 4), (int)(NF / 4));

    proj_gemm<<<dim3(8, 64, 3), 512, 0, stream>>>(Xq, Xk, Xv, Wq, Wk, Wv,
                                                  wq_b, wk_b, wv_b, Qh, Kh, Vt);
    attn_kernel<<<dim3(16, 64), 256, 0, stream>>>(Qh, Kh, Vt, mask, O);
    fc_kernel<<<128, 256, 0, stream>>>(O, Wf, fc_b, (float*)d_out);
}

// Round 21
// 178.576 us; speedup vs baseline: 1.0712x; 1.0326x over previous
//
#include <hip/hip_runtime.h>
#include <stdint.h>

#define S_LEN 2048
#define DK 1024
#define NH 16
#define DH 64
#define LOG2E 1.4426950408889634f
#define M_FIX 10.0f

typedef __attribute__((ext_vector_type(8))) short bf16x8;
typedef __attribute__((ext_vector_type(4))) float f32x4;

__device__ __forceinline__ unsigned short f2bf(float f) {
    union { float f; uint32_t u; } v; v.f = f;
    return (unsigned short)((v.u + 0x7fffu + ((v.u >> 16) & 1u)) >> 16);
}

__device__ __forceinline__ float fast_exp2(float x) {
#if __has_builtin(__builtin_amdgcn_exp2f)
    return __builtin_amdgcn_exp2f(x);
#else
    return exp2f(x);
#endif
}

// packed f32 pair -> [lo16=bf16(a), hi16=bf16(b)] in one VALU op (RNE)
__device__ __forceinline__ uint32_t cvt_pk_bf16(float a, float b) {
    uint32_t r;
    asm("v_cvt_pk_bf16_f32 %0, %1, %2" : "=v"(r) : "v"(a), "v"(b));
    return r;
}

__device__ __forceinline__ void gload_lds16(const void* g, void* l) {
    __builtin_amdgcn_global_load_lds((const __attribute__((address_space(1))) void*)g,
                                     (__attribute__((address_space(3))) void*)l, 16, 0, 0);
}

// ---------------- f32 -> bf16 convert: all 7 tensors in one launch ----------------
__global__ __launch_bounds__(256) void cvt7_kernel(
    const float* __restrict__ a0, const float* __restrict__ a1, const float* __restrict__ a2,
    const float* __restrict__ a3, const float* __restrict__ a4, const float* __restrict__ a5,
    const float* __restrict__ a6,
    unsigned short* __restrict__ o0, unsigned short* __restrict__ o1, unsigned short* __restrict__ o2,
    unsigned short* __restrict__ o3, unsigned short* __restrict__ o4, unsigned short* __restrict__ o5,
    unsigned short* __restrict__ o6,
    int n4_big, int n4_w, int n4_f)
{
    const int y = blockIdx.y;
    const float* in = (y == 0) ? a0 : (y == 1) ? a1 : (y == 2) ? a2 :
                      (y == 3) ? a3 : (y == 4) ? a4 : (y == 5) ? a5 : a6;
    unsigned short* out = (y == 0) ? o0 : (y == 1) ? o1 : (y == 2) ? o2 :
                          (y == 3) ? o3 : (y == 4) ? o4 : (y == 5) ? o5 : o6;
    const int n4 = (y < 3) ? n4_big : ((y < 6) ? n4_w : n4_f);
    const float4* pin = (const float4*)in;
    ushort4* pout = (ushort4*)out;
    int i = blockIdx.x * blockDim.x + threadIdx.x;
    int stride = gridDim.x * blockDim.x;
    for (; i < n4; i += stride) {
        float4 v = pin[i];
        ushort4 o;
        o.x = f2bf(v.x); o.y = f2bf(v.y); o.z = f2bf(v.z); o.w = f2bf(v.w);
        pout[i] = o;
    }
}

// ---------------- QKV projection GEMM (BK=64 = 2x BK=32 sub-tiles, 512 thr, 2-buf) ----------------
// 16 K-steps (barriers halved vs BK=32). LDS As/Bs[buf][sub][128][32]: each sub-tile
// uses the proven 0-conflict rotation layout verbatim (reads add k32*4096). 2 buffers
// x 32KB = 64KB -> 2 blocks/CU @512thr = 16 waves/CU. Proven 2-phase prefetch:
// stage(t+1) issued right after __syncthreads, drained by the next one.
__global__ __launch_bounds__(512) void proj_gemm(
    const unsigned short* __restrict__ Xq, const unsigned short* __restrict__ Xk, const unsigned short* __restrict__ Xv,
    const unsigned short* __restrict__ Wq, const unsigned short* __restrict__ Wk, const unsigned short* __restrict__ Wv,
    const float* __restrict__ bq, const float* __restrict__ bk, const float* __restrict__ bv,
    unsigned short* __restrict__ Qh, unsigned short* __restrict__ Kh, unsigned short* __restrict__ Vt)
{
    // bijective remap: d = x + 8y + 512z; k = XCD slot, s = per-XCD sequence
    const int d = blockIdx.x + (blockIdx.y << 3) + (blockIdx.z << 9);
    const int k = d & 7, s = d >> 3;
    const int nn = s & 7;
    const int mz = ((s >> 3) << 3) + k;      // 0..191
    const int m0 = (mz & 63) * 128;
    const int z = mz >> 6;

    const unsigned short* X = (z == 0) ? Xq : ((z == 1) ? Xk : Xv);
    const unsigned short* W = (z == 0) ? Wq : ((z == 1) ? Wk : Wv);
    const float* bias = (z == 0) ? bq : ((z == 1) ? bk : bv);

    const int n0 = nn * 128;
    const int tid = threadIdx.x;
    const int w = tid >> 6;                  // 0..7
    const int l = tid & 63;
    const int wm = w >> 2, wn = w & 3;       // 2m x 4n wave grid
    const int g = l >> 4, c = l & 15;

    __shared__ __align__(16) unsigned short As[2][2 * 128 * 32];
    __shared__ __align__(16) unsigned short Bs[2][2 * 128 * 32];

    f32x4 acc[4][2] = {};

    const int srow = l >> 2;                                 // row within 16-block
    const int schunk = (((l & 3) - (l >> 3)) & 3) * 8;       // rotation source chunk

    // wave w stages sub-tile (w>>2), row block 32*(w&3), for both A and B
    const int sub = w >> 2;
    const int rb = 32 * (w & 3);

    auto stage = [&](int kk, int buf) {
#pragma unroll
        for (int i = 0; i < 2; ++i) {
            int r0 = rb + 16 * i;
            gload_lds16(X + (size_t)(m0 + r0 + srow) * DK + kk + 32 * sub + schunk,
                        &As[buf][sub * 4096 + r0 * 32]);
            gload_lds16(W + (size_t)(n0 + r0 + srow) * DK + kk + 32 * sub + schunk,
                        &Bs[buf][sub * 4096 + r0 * 32]);
        }
    };

    // prologue
    stage(0, 0);

    for (int t = 0; t < 16; ++t) {
        const int buf = t & 1;
        __syncthreads();   // stage(t) drained (vmcnt0+lgkm0); prev step's LDS reads done

        if (t < 15) stage((t + 1) << 6, buf ^ 1);

        const int rchunk = 8 * ((g + (c >> 1)) & 3);   // conflict-free rotation read
        __builtin_amdgcn_s_setprio(1);
#pragma unroll
        for (int k32 = 0; k32 < 2; ++k32) {
            bf16x8 a[4], bb[2];
#pragma unroll
            for (int mi = 0; mi < 4; ++mi)
                a[mi] = *(const bf16x8*)&As[buf][k32 * 4096 + (64 * wm + 16 * mi + c) * 32 + rchunk];
#pragma unroll
            for (int nj = 0; nj < 2; ++nj)
                bb[nj] = *(const bf16x8*)&Bs[buf][k32 * 4096 + (32 * wn + 16 * nj + c) * 32 + rchunk];
#pragma unroll
            for (int mi = 0; mi < 4; ++mi)
#pragma unroll
                for (int nj = 0; nj < 2; ++nj)
                    acc[mi][nj] = __builtin_amdgcn_mfma_f32_16x16x32_bf16(a[mi], bb[nj], acc[mi][nj], 0, 0, 0);
        }
        __builtin_amdgcn_s_setprio(0);
    }

    // Q pre-scaled by LOG2E/8 (attn exp2's the raw QK^T sum)
    const float scale = (z == 0) ? (0.125f * LOG2E) : 1.0f;
#pragma unroll
    for (int mi = 0; mi < 4; ++mi) {
#pragma unroll
        for (int nj = 0; nj < 2; ++nj) {
            int col = n0 + 32 * wn + 16 * nj + c;
            float bval = bias[col];
            int h = col >> 6, dh = col & 63;
            int row0 = m0 + 64 * wm + 16 * mi + 4 * g;
            int b = row0 >> 11, ss = row0 & 2047;
            if (z != 2) {
                unsigned short* Out = (z == 0) ? Qh : Kh;
#pragma unroll
                for (int r = 0; r < 4; ++r) {
                    float v = (acc[mi][nj][r] + bval) * scale;
                    Out[((size_t)(b * NH + h) * S_LEN + (ss + r)) * DH + dh] = f2bf(v);
                }
            } else {
                ushort4 o;
                o.x = f2bf(acc[mi][nj][0] + bval);
                o.y = f2bf(acc[mi][nj][1] + bval);
                o.z = f2bf(acc[mi][nj][2] + bval);
                o.w = f2bf(acc[mi][nj][3] + bval);
                // pair-interleaved key order within each 32-block
                int q = (ss >> 2) & 7;
                int newpos = (ss & ~31) + 8 * (q & 3) + 4 * (q >> 2);
                *(ushort4*)&Vt[((size_t)(b * NH + h) * DH + dh) * S_LEN + newpos] = o;
            }
        }
    }
}

// ---------------- Flash attention (KVBLK=64: one barrier per 64 keys) ----------------
// Unchanged from round-18/20 green (~73 us, 0 bank conflicts).
__global__ __launch_bounds__(256, 4) void attn_kernel(
    const unsigned short* __restrict__ Qh, const unsigned short* __restrict__ Kh,
    const unsigned short* __restrict__ Vt, const int* __restrict__ maskI,
    unsigned short* __restrict__ O)
{
    // XCD swizzle: 1024 wgs, 8 XCDs -> 128 contiguous wgs per XCD (8 bh each)
    const int id = blockIdx.x + (blockIdx.y << 4);
    const int swzid = (id & 7) * 128 + (id >> 3);
    const int q0 = (swzid & 15) * 128;
    const int bh = swzid >> 4;
    const int b = bh >> 4, h = bh & 15;
    const int tid = threadIdx.x, w = tid >> 6, l = tid & 63;
    const int g = l >> 4, c = l & 15;

    __shared__ __align__(16) unsigned short Ks[2][4096];   // [u][32key x 64dh] x2 sub-tiles
    __shared__ __align__(16) unsigned short Vs[2][4096];   // [u][64dh x 32key] pair-rotated
    __shared__ __align__(16) float mskA[S_LEN];

    bf16x8 qf[2][2];
    const size_t qbase = (size_t)bh * S_LEN + q0 + 32 * w;
#pragma unroll
    for (int mi = 0; mi < 2; ++mi)
#pragma unroll
        for (int k32 = 0; k32 < 2; ++k32)
            qf[mi][k32] = *(const bf16x8*)&Qh[(qbase + 16 * mi + c) * DH + k32 * 32 + 8 * g];

    f32x4 ao[2][4] = {};
    f32x4 ls[2] = {};
    bf16x8 ones;
#pragma unroll
    for (int j = 0; j < 8; ++j) ones[j] = (short)0x3F80;  // bf16 1.0

    // staging source swizzles
    const int kswz = ((l & 7) ^ (l >> 3)) * 8;               // K: 8-chunk XOR (conflict-free)
    const int vrow = l >> 2;                                 // V: stage row within wave's 16
    const int vsrc = (((l & 3) - (l >> 3)) & 3) * 8;         // quad-pair rotation source

    auto stageKV = [&](int kv, int buf) {
#pragma unroll
        for (int u = 0; u < 2; ++u) {
            int kvs = kv + 32 * u;
            gload_lds16(Kh + ((size_t)bh * S_LEN + kvs + 8 * w + (l >> 3)) * DH + kswz,
                        &Ks[buf][u * 2048 + w * 512]);
            gload_lds16(Vt + ((size_t)bh * DH + 16 * w + vrow) * S_LEN + kvs + vsrc,
                        &Vs[buf][u * 2048 + w * 512]);
        }
    };

    // prologue: stage tile 0 + mask preload
    stageKV(0, 0);
    {
        const int4* mp = (const int4*)(maskI + b * S_LEN);
#pragma unroll
        for (int i = 0; i < 2; ++i) {
            int idx = tid + 256 * i;
            int4 m = mp[idx];
            float4 f;
            f.x = m.x ? (-M_FIX * LOG2E) : -3e38f;
            f.y = m.y ? (-M_FIX * LOG2E) : -3e38f;
            f.z = m.z ? (-M_FIX * LOG2E) : -3e38f;
            f.w = m.w ? (-M_FIX * LOG2E) : -3e38f;
            *(float4*)&mskA[idx * 4] = f;
        }
    }

    for (int t = 0; t < 32; ++t) {
        const int cur = t & 1;
        const int kv0 = t << 6;
        __syncthreads();   // stage(t) drained (vmcnt0+lgkm0); prev tile's LDS reads done

        if (t < 31) stageKV(kv0 + 64, cur ^ 1);

#pragma unroll
        for (int u = 0; u < 2; ++u) {
            const int base = u * 2048;
            const int kv0s = kv0 + 32 * u;

            // mask bias (also the QK C-operand), hoisted above the MFMAs
            float4 mk0 = *(const float4*)&mskA[kv0s + 4 * g];
            float4 mk1 = *(const float4*)&mskA[kv0s + 16 + 4 * g];
            f32x4 sf[2][2];
            sf[0][0] = f32x4{mk0.x, mk0.y, mk0.z, mk0.w};
            sf[1][0] = sf[0][0];
            sf[0][1] = f32x4{mk1.x, mk1.y, mk1.z, mk1.w};
            sf[1][1] = sf[0][1];

            // Swapped QK^T: sf[mi][nj] = D[key=16nj+4g+r][q=16mi+c] + mask bias
            __builtin_amdgcn_s_setprio(1);
#pragma unroll
            for (int nj = 0; nj < 2; ++nj) {
                int krow = 16 * nj + c;
#pragma unroll
                for (int k32 = 0; k32 < 2; ++k32) {
                    int chunk = (k32 * 4 + g) ^ (krow & 7);
                    bf16x8 kf = *(const bf16x8*)&Ks[cur][base + krow * 64 + chunk * 8];
#pragma unroll
                    for (int mi = 0; mi < 2; ++mi)
                        sf[mi][nj] = __builtin_amdgcn_mfma_f32_16x16x32_bf16(kf, qf[mi][k32], sf[mi][nj], 0, 0, 0);
                }
            }
            __builtin_amdgcn_s_setprio(0);

            // softmax: p = exp2(sf) directly (scale+mask pre-folded)
            bf16x8 pf[2];
#pragma unroll
            for (int mi = 0; mi < 2; ++mi) {
                float e00 = fast_exp2(sf[mi][0][0]);
                float e01 = fast_exp2(sf[mi][0][1]);
                float e02 = fast_exp2(sf[mi][0][2]);
                float e03 = fast_exp2(sf[mi][0][3]);
                float e10 = fast_exp2(sf[mi][1][0]);
                float e11 = fast_exp2(sf[mi][1][1]);
                float e12 = fast_exp2(sf[mi][1][2]);
                float e13 = fast_exp2(sf[mi][1][3]);
                union { uint32_t u2[4]; bf16x8 v; } pu;
                pu.u2[0] = cvt_pk_bf16(e00, e01);
                pu.u2[1] = cvt_pk_bf16(e02, e03);
                pu.u2[2] = cvt_pk_bf16(e10, e11);
                pu.u2[3] = cvt_pk_bf16(e12, e13);
                pf[mi] = pu.v;
            }

            // PV: ao += P.V^T (k-axis = pi(g,j)); ls += P.1
            __builtin_amdgcn_s_setprio(1);
#pragma unroll
            for (int nc = 0; nc < 4; ++nc) {
                int row = 16 * nc + c;
                int s16 = (g + (c >> 1)) & 3;
                bf16x8 vf = *(const bf16x8*)&Vs[cur][base + row * 32 + 8 * s16];
#pragma unroll
                for (int mi = 0; mi < 2; ++mi)
                    ao[mi][nc] = __builtin_amdgcn_mfma_f32_16x16x32_bf16(pf[mi], vf, ao[mi][nc], 0, 0, 0);
            }
#pragma unroll
            for (int mi = 0; mi < 2; ++mi)
                ls[mi] = __builtin_amdgcn_mfma_f32_16x16x32_bf16(pf[mi], ones, ls[mi], 0, 0, 0);
            __builtin_amdgcn_s_setprio(0);
        }
    }

#pragma unroll
    for (int mi = 0; mi < 2; ++mi)
#pragma unroll
        for (int r = 0; r < 4; ++r) {
            int s = q0 + 32 * w + 16 * mi + 4 * g + r;
            float inv = 1.0f / ls[mi][r];
#pragma unroll
            for (int nc = 0; nc < 4; ++nc) {
                int dh = 16 * nc + c;
                O[(size_t)(b * S_LEN + s) * 1024 + h * DH + dh] = f2bf(ao[mi][nc][r] * inv);
            }
        }
}

// ---------------- fc GEMM + grouped softmax (3-buf counted-vmcnt pipeline) ----------------
__global__ __launch_bounds__(256) void fc_kernel(
    const unsigned short* __restrict__ O, const unsigned short* __restrict__ Wf,
    const float* __restrict__ bfc, float* __restrict__ out)
{
    const int m0 = blockIdx.x * 64;
    const int tid = threadIdx.x, w = tid >> 6, l = tid & 63;
    const int g = l >> 4, c = l & 15;

    __shared__ __align__(16) unsigned short As[3][64 * 32];
    __shared__ __align__(16) unsigned short Bs[3][128 * 32];

    f32x4 acc[8] = {};

    const int srow = l >> 2;
    const int schunk = (((l & 3) - (l >> 3)) & 3) * 8;

    auto stage = [&](int kk, int buf) {
        gload_lds16(O + (size_t)(m0 + 16 * w + srow) * DK + kk + schunk, &As[buf][16 * w * 32]);
#pragma unroll
        for (int j = 0; j < 2; ++j) {
            int r0 = 32 * w + 16 * j;
            gload_lds16(Wf + (size_t)(r0 + srow) * DK + kk + schunk, &Bs[buf][r0 * 32]);
        }
    };

    stage(0, 0);
    stage(32, 1);

    int cur = 0;
    for (int step = 0; step < 32; ++step) {
        if (step < 31) asm volatile("s_waitcnt vmcnt(3)" ::: "memory");
        else           asm volatile("s_waitcnt vmcnt(0)" ::: "memory");
        __builtin_amdgcn_s_barrier();
        __builtin_amdgcn_sched_barrier(0);

        if (step < 30) {
            int nb = cur + 2; if (nb >= 3) nb -= 3;
            stage((step + 2) << 5, nb);
        }

        const int rchunk = 8 * ((g + (c >> 1)) & 3);
        bf16x8 a = *(const bf16x8*)&As[cur][(16 * w + c) * 32 + rchunk];
        bf16x8 bb[8];
#pragma unroll
        for (int nj = 0; nj < 8; ++nj)
            bb[nj] = *(const bf16x8*)&Bs[cur][(16 * nj + c) * 32 + rchunk];
        __builtin_amdgcn_s_setprio(1);
#pragma unroll
        for (int nj = 0; nj < 8; ++nj)
            acc[nj] = __builtin_amdgcn_mfma_f32_16x16x32_bf16(a, bb[nj], acc[nj], 0, 0, 0);
        __builtin_amdgcn_s_setprio(0);

        ++cur; if (cur == 3) cur = 0;
    }

#pragma unroll
    for (int r = 0; r < 4; ++r) {
        int row = m0 + 16 * w + (l >> 4) * 4 + r;
#pragma unroll
        for (int par = 0; par < 2; ++par) {
            float v[4];
#pragma unroll
            for (int e = 0; e < 4; ++e) {
                int col = 16 * (2 * e + par) + (l & 15);
                v[e] = acc[2 * e + par][r] + bfc[col];
            }
            float mx = fmaxf(fmaxf(v[0], v[1]), fmaxf(v[2], v[3]));
            float ex[4], ssum = 0.f;
#pragma unroll
            for (int e = 0; e < 4; ++e) { ex[e] = fast_exp2((v[e] - mx) * LOG2E); ssum += ex[e]; }
            float inv = 1.0f / ssum;
#pragma unroll
            for (int e = 0; e < 4; ++e) {
                int col = 16 * (2 * e + par) + (l & 15);
                out[(size_t)row * 128 + col] = ex[e] * inv;
            }
        }
    }
}

extern "C" void kernel_launch(void* const* d_in, const int* in_sizes, int n_in,
                              void* d_out, int out_size, void* d_ws, size_t ws_size,
                              hipStream_t stream) {
    (void)in_sizes; (void)n_in; (void)out_size; (void)ws_size;
    const float* q    = (const float*)d_in[0];
    const float* k    = (const float*)d_in[1];
    const float* v    = (const float*)d_in[2];
    const int*   mask = (const int*)d_in[3];
    const float* wq_w = (const float*)d_in[4];
    const float* wq_b = (const float*)d_in[5];
    const float* wk_w = (const float*)d_in[6];
    const float* wk_b = (const float*)d_in[7];
    const float* wv_w = (const float*)d_in[8];
    const float* wv_b = (const float*)d_in[9];
    const float* fc_w = (const float*)d_in[10];
    const float* fc_b = (const float*)d_in[11];

    const size_t NX = (size_t)8192 * 1024;
    const size_t NW = (size_t)1024 * 1024;
    const size_t NF = (size_t)128 * 1024;

    unsigned short* Xq = (unsigned short*)d_ws;
    unsigned short* Xk = Xq + NX;
    unsigned short* Xv = Xk + NX;
    unsigned short* Wq = Xv + NX;
    unsigned short* Wk = Wq + NW;
    unsigned short* Wv = Wk + NW;
    unsigned short* Wf = Wv + NW;
    unsigned short* Qh = Wf + NF;
    unsigned short* Kh = Qh + NX;
    unsigned short* Vt = Kh + NX;
    unsigned short* O  = Xq;  // Xq dead after proj; reuse for attention output

    cvt7_kernel<<<dim3(2048, 7), 256, 0, stream>>>(q, k, v, wq_w, wk_w, wv_w, fc_w,
                                                   Xq, Xk, Xv, Wq, Wk, Wv, Wf,
                                                   (int)(NX / 4), (int)(NW / 4), (int)(NF / 4));

    proj_gemm<<<dim3(8, 64, 3), 512, 0, stream>>>(Xq, Xk, Xv, Wq, Wk, Wv,
                                                  wq_b, wk_b, wv_b, Qh, Kh, Vt);
    attn_kernel<<<dim3(16, 64), 256, 0, stream>>>(Qh, Kh, Vt, mask, O);
    fc_kernel<<<128, 256, 0, stream>>>(O, Wf, fc_b, (float*)d_out);
}